// Round 2
// baseline (1111.812 us; speedup 1.0000x reference)
//
#include <hip/hip_runtime.h>
#include <math.h>

// SOCPooling on MI355X (gfx950):
//   x [128,1024,768] f32, W [24,768] f32 -> out [128,300] f32
// k1: projection p = x W^T fused with per-block partial S = P^T P, s = sum(p).
//     ROUND 2: DRAM-friendly re-tile. Old scheme staged (256 rows x 128B) per
//     chunk -> every request a 128B page-miss at 3072B stride -> delivered BW
//     capped ~1.1 TB/s, latency inflated to ~35k cyc/chunk (Little's law).
//     New scheme: row-groups of 64 rows, col-chunks of 96 floats = 384B
//     bursts (3 consecutive lines per row per visit, 3x fewer activations);
//     the 4 waves split the 96 cols (24 each) so W stays wave-uniform
//     (SGPR s_load broadcast); per-group cross-wave combine via LDS atomicAdd
//     into P. Barrier structure = proven round-0 drain style (one variable
//     changed this round). XOR-quad swizzle on the GLOBAL side keeps
//     compute-side ds_read_b128 conflict-free.
// k2: cov finalize + one-sided Jacobi eigh (unchanged).

#define AS1 __attribute__((address_space(1)))
#define AS3 __attribute__((address_space(3)))

#define B_      128
#define T_      1024
#define D_      768
#define K_      24
#define ROWS    256      // rows per k1 block
#define BPB     4        // k1 blocks per batch
#define GROWS   64       // rows per row-group
#define NG      4        // row-groups per block
#define DCOLS   96       // cols per chunk (384 B per row)
#define NCC     8        // col-chunks per row-group (768/96)
#define NCH     32       // total chunks per block (NG*NCC)
#define CHW     6144     // words per chunk buffer (64 rows * 96 words)
#define GRPB    196608   // bytes per row-group slab (64*3072)
#define PSTRIDE 28       // padded P row stride (112 B, 16B-aligned)
#define NACC    600      // 576 S entries + 24 sums
#define NPAIR   300
#define SWEEPS  8

__global__ __launch_bounds__(256, 2) void socpool_proj(
    const float* __restrict__ x, const float* __restrict__ W,
    float* __restrict__ partial) {
  // 2 chunk buffers (2*24576 B) + P (256*28*4 = 28672 B) = 77824 B <= 80 KiB
  __shared__ float smem[2 * CHW + ROWS * PSTRIDE];
  float* P = smem + 2 * CHW;
  const int tid  = threadIdx.x;
  const int b    = blockIdx.x >> 2;
  const int rb   = blockIdx.x & 3;
  const int wv   = tid >> 6;   // wave id = col-phase within chunk
  const int l    = tid & 63;   // lane = row within group
  const char* xslab = (const char*)(x + ((size_t)b * T_ + rb * ROWS) * D_);

  // zero P (each P row is atomically accumulated exactly once, by one group)
  for (int i = tid; i < ROWS * PSTRIDE; i += 256) P[i] = 0.f;

  float acc[K_];
#pragma unroll
  for (int k = 0; k < K_; ++k) acc[k] = 0.f;

  // ---- staging address precompute (loop-invariant per lane) ----
  // flat byte slot f = (wv*6+i)*1024 + l*16 within the 24 KiB chunk.
  // f -> (row = f/384, srel = (f%384)/16). Storage quad srel holds LOGICAL
  // quad Q = (srel&~7)|((srel&7)^(row&7)) (XOR pre-swizzle on global side).
  // Global byte (within group slab) = row*3072 + cc*384 + Q*16.
  int goff[6];
#pragma unroll
  for (int i = 0; i < 6; ++i) {
    const int f    = (wv * 6 + i) * 1024 + l * 16;
    const int n    = f >> 7;              // f/128, < 192
    const int row  = (n * 171) >> 9;      // exact /3 for n < 512
    const int srel = (f - row * 384) >> 4;  // 0..23
    const int Q    = (srel & ~7) | ((srel & 7) ^ (row & 7));
    goff[i] = row * 3072 + (Q << 4);
  }
  // compute-side LDS word offsets: thread reads logical quads Q = wv*6+q of
  // row l; stored at s = (Q&~7)|((Q&7)^(l&7)) -> word l*96 + 4*s.
  int xoff[6];
#pragma unroll
  for (int q = 0; q < 6; ++q) {
    const int Q = wv * 6 + q;
    const int s = (Q & ~7) | ((Q & 7) ^ (l & 7));
    xoff[q] = l * 96 + (s << 2);
  }

  auto issue = [&](int c, int bufsel) {
    const int g = c >> 3, cc = c & 7;
    const char* gbase = xslab + (size_t)g * GRPB + cc * 384;
    float* lb = smem + bufsel * CHW + wv * 1536;  // wave-uniform base
#pragma unroll
    for (int i = 0; i < 6; ++i)
      __builtin_amdgcn_global_load_lds((const AS1 void*)(gbase + goff[i]),
                                       (AS3 void*)(lb + i * 256), 16, 0, 0);
  };

  issue(0, 0);
  __syncthreads();  // P zeroed + chunk 0 resident (drains vmcnt+lgkmcnt)
  for (int c = 0; c < NCH; ++c) {
    if (c + 1 < NCH) issue(c + 1, (c + 1) & 1);
    const float* buf = smem + (c & 1) * CHW;
    // W cols for this (chunk, wave): float col base = cc*96 + wv*24 + q*4,
    // wave-uniform -> scalar loads with k*768 + q*4 immediates.
    const float* wb = W + (c & 7) * DCOLS + wv * 24;
#pragma unroll
    for (int q = 0; q < 6; ++q) {
      float4 xv = *(const float4*)(&buf[xoff[q]]);
      const float* wp = wb + (q << 2);
#pragma unroll
      for (int k = 0; k < K_; ++k) {
        const float* wr = wp + (size_t)k * D_;
        acc[k] = fmaf(xv.x, wr[0], acc[k]);
        acc[k] = fmaf(xv.y, wr[1], acc[k]);
        acc[k] = fmaf(xv.z, wr[2], acc[k]);
        acc[k] = fmaf(xv.w, wr[3], acc[k]);
      }
    }
    if ((c & 7) == 7) {
      // row-group done: combine the 4 waves' col-phase partials into P
      const int rbase = ((c >> 3) * GROWS + l) * PSTRIDE;
#pragma unroll
      for (int k = 0; k < K_; ++k) {
        atomicAdd(&P[rbase + k], acc[k]);
        acc[k] = 0.f;
      }
    }
    __syncthreads();  // chunk c+1 drained; buffer & P-adds ordered
  }

  // per-block partial S[k][l] (full 24x24, quad tasks) and column sums
  float* outp = partial + (size_t)blockIdx.x * NACC;
  if (tid < 144) {
    const int k = tid / 6;
    const int q = (tid % 6) * 4;
    float a0=0.f,a1=0.f,a2=0.f,a3=0.f,b0=0.f,b1=0.f,b2=0.f,b3=0.f;
    for (int t = 0; t < ROWS; t += 2) {
      float  pk0 = P[t * PSTRIDE + k];
      float4 pq0 = *(const float4*)(&P[t * PSTRIDE + q]);
      float  pk1 = P[(t + 1) * PSTRIDE + k];
      float4 pq1 = *(const float4*)(&P[(t + 1) * PSTRIDE + q]);
      a0 = fmaf(pk0, pq0.x, a0); a1 = fmaf(pk0, pq0.y, a1);
      a2 = fmaf(pk0, pq0.z, a2); a3 = fmaf(pk0, pq0.w, a3);
      b0 = fmaf(pk1, pq1.x, b0); b1 = fmaf(pk1, pq1.y, b1);
      b2 = fmaf(pk1, pq1.z, b2); b3 = fmaf(pk1, pq1.w, b3);
    }
    outp[k * K_ + q + 0] = a0 + b0;
    outp[k * K_ + q + 1] = a1 + b1;
    outp[k * K_ + q + 2] = a2 + b2;
    outp[k * K_ + q + 3] = a3 + b3;
  } else if (tid < 168) {
    const int k = tid - 144;
    float s0 = 0.f, s1 = 0.f;
    for (int t = 0; t < ROWS; t += 2) {
      s0 += P[t * PSTRIDE + k];
      s1 += P[(t + 1) * PSTRIDE + k];
    }
    outp[576 + k] = s0 + s1;
  }
}

__global__ __launch_bounds__(64, 1) void socpool_eig(
    const float* __restrict__ partial, float* __restrict__ out) {
  __shared__ float Amat[K_ * 25];
  __shared__ float Qs[K_ * 25];
  __shared__ float lv[K_];
  __shared__ float raw[NACC];
  __shared__ float Xc[K_ * PSTRIDE];  // column-exchange buffer
  const int tid = threadIdx.x;  // 64 threads = 1 wave
  const int b = blockIdx.x;

  // combine the 4 per-block partials
#pragma unroll
  for (int i = 0; i < 10; ++i) {
    int e = tid + (i << 6);
    if (e < NACC) {
      float v = 0.f;
#pragma unroll
      for (int jj = 0; jj < BPB; ++jj)
        v += partial[(size_t)(b * BPB + jj) * NACC + e];
      raw[e] = v;
    }
  }
  __syncthreads();

  const float inv_n   = 1.f / 1024.f;
  const float inv_nm1 = 1.f / (1023.f + 1e-6f);
  float cv[9];
#pragma unroll
  for (int i = 0; i < 9; ++i) {
    int e = tid + (i << 6);            // < 576 always
    int k = e / K_, l = e % K_;
    cv[i] = (raw[e] - raw[576 + k] * raw[576 + l] * inv_n) * inv_nm1;
    Amat[k * 25 + l] = cv[i];
  }
  __syncthreads();
  float tr = 0.f;
#pragma unroll
  for (int k = 0; k < K_; ++k) tr += Amat[k * 25 + k];
  float sym[9];
#pragma unroll
  for (int i = 0; i < 9; ++i) {
    int e = tid + (i << 6);
    int k = e / K_, l = e % K_;
    sym[i] = cv[i] + Amat[l * 25 + k];
  }
  __syncthreads();
  const float sc = 0.5f / (tr + 1e-6f);
#pragma unroll
  for (int i = 0; i < 9; ++i) {
    int e = tid + (i << 6);
    int k = e / K_, l = e % K_;
    Amat[k * 25 + l] = sym[i] * sc + ((k == l) ? 1e-4f : 0.f);
  }
  __syncthreads();

  // ---- one-sided Jacobi: lane j holds column j as float4 Gv[6] ----
  const int j = tid;
  float4 Gv[6];
#pragma unroll
  for (int q = 0; q < 6; ++q) {
    // A symmetric: column j == row j (row read; init-only, alignment moot)
    Gv[q].x = (j < K_) ? Amat[j * 25 + 4*q + 0] : 0.f;
    Gv[q].y = (j < K_) ? Amat[j * 25 + 4*q + 1] : 0.f;
    Gv[q].z = (j < K_) ? Amat[j * 25 + 4*q + 2] : 0.f;
    Gv[q].w = (j < K_) ? Amat[j * 25 + 4*q + 3] : 0.f;
  }

  for (int sweep = 0; sweep < SWEEPS; ++sweep) {
    for (int rr = 0; rr < 23; ++rr) {
      // circle-method round-robin: fixed player 23; inv(2) mod 23 = 12
      int partner;
      if (j == 23) {
        partner = (12 * rr) % 23;
      } else if (j < 23) {
        partner = rr - j;
        if (partner < 0) partner += 23;
        if (partner == j) partner = 23;
      } else {
        partner = j;  // idle lanes: identity rotation below
      }
      // exchange via LDS: 6 b128 writes + 6 b128 reads (stride 28 -> no
      // bank conflicts), instead of 25 latency-serialized ds_bpermute
      if (j < K_) {
#pragma unroll
        for (int q = 0; q < 6; ++q)
          *(float4*)(&Xc[j * PSTRIDE + (q << 2)]) = Gv[q];
      }
      __syncthreads();
      const int pcol = (partner < K_) ? partner : 0;
      float4 O[6];
#pragma unroll
      for (int q = 0; q < 6; ++q)
        O[q] = *(const float4*)(&Xc[pcol * PSTRIDE + (q << 2)]);
      // three dots, 12 independent FMA chains
      float a0=0.f,a1=0.f,a2=0.f,a3=0.f;   // nn  = G.G
      float b0=0.f,b1=0.f,b2=0.f,b3=0.f;   // nno = O.O
      float c0=0.f,c1=0.f,c2=0.f,c3=0.f;   // gpq = G.O
#pragma unroll
      for (int q = 0; q < 6; ++q) {
        a0 = fmaf(Gv[q].x, Gv[q].x, a0); a1 = fmaf(Gv[q].y, Gv[q].y, a1);
        a2 = fmaf(Gv[q].z, Gv[q].z, a2); a3 = fmaf(Gv[q].w, Gv[q].w, a3);
        b0 = fmaf(O[q].x, O[q].x, b0);   b1 = fmaf(O[q].y, O[q].y, b1);
        b2 = fmaf(O[q].z, O[q].z, b2);   b3 = fmaf(O[q].w, O[q].w, b3);
        c0 = fmaf(Gv[q].x, O[q].x, c0);  c1 = fmaf(Gv[q].y, O[q].y, c1);
        c2 = fmaf(Gv[q].z, O[q].z, c2);  c3 = fmaf(Gv[q].w, O[q].w, c3);
      }
      float nn  = (a0 + a1) + (a2 + a3);
      float nno = (b0 + b1) + (b2 + b3);
      float gpq = (c0 + c1) + (c2 + c3);
      const bool low = (j < partner);
      float app = low ? nn : nno;
      float aqq = low ? nno : nn;
      float cc = 1.f, ss = 0.f;
      if (j != partner && fabsf(gpq) > 1e-30f) {
        float tau = (aqq - app) / (2.f * gpq);
        float t = 1.f / (fabsf(tau) + sqrtf(1.f + tau * tau));
        if (tau < 0.f) t = -t;
        cc = 1.f / sqrtf(1.f + t * t);
        ss = t * cc;
      }
      float sg = low ? -ss : ss;  // p' = c p - s q ; q' = s p + c q
#pragma unroll
      for (int q = 0; q < 6; ++q) {
        Gv[q].x = fmaf(sg, O[q].x, cc * Gv[q].x);
        Gv[q].y = fmaf(sg, O[q].y, cc * Gv[q].y);
        Gv[q].z = fmaf(sg, O[q].z, cc * Gv[q].z);
        Gv[q].w = fmaf(sg, O[q].w, cc * Gv[q].w);
      }
      __syncthreads();  // Xc reuse next round
    }
  }

  // eigenvalues = column norms (A SPD), eigenvectors = normalized columns
  if (j < K_) {
    float n0=0.f,n1=0.f,n2=0.f,n3=0.f;
#pragma unroll
    for (int q = 0; q < 6; ++q) {
      n0 = fmaf(Gv[q].x, Gv[q].x, n0); n1 = fmaf(Gv[q].y, Gv[q].y, n1);
      n2 = fmaf(Gv[q].z, Gv[q].z, n2); n3 = fmaf(Gv[q].w, Gv[q].w, n3);
    }
    float lam = sqrtf((n0 + n1) + (n2 + n3));
    lv[j] = logf(fmaxf(lam, 1e-6f));
    float inv = 1.f / fmaxf(lam, 1e-20f);
#pragma unroll
    for (int q = 0; q < 6; ++q) {
      Qs[(4*q + 0) * 25 + j] = Gv[q].x * inv;
      Qs[(4*q + 1) * 25 + j] = Gv[q].y * inv;
      Qs[(4*q + 2) * 25 + j] = Gv[q].z * inv;
      Qs[(4*q + 3) * 25 + j] = Gv[q].w * inv;
    }
  }
  __syncthreads();

  // log_cov = Q diag(lv) Q^T, upper triangle row-major (matches triu_indices)
  for (int e = tid; e < NPAIR; e += 64) {
    int i = 0, base = 0;
    while (i < K_ - 1 && base + (K_ - i) <= e) { base += K_ - i; ++i; }
    int jj = i + (e - base);
    float sum = 0.f;
#pragma unroll
    for (int k = 0; k < K_; ++k)
      sum = fmaf(Qs[i * 25 + k] * lv[k], Qs[jj * 25 + k], sum);
    out[(size_t)b * NPAIR + e] = sum;
  }
}

extern "C" void kernel_launch(void* const* d_in, const int* in_sizes, int n_in,
                              void* d_out, int out_size, void* d_ws, size_t ws_size,
                              hipStream_t stream) {
  const float* x = (const float*)d_in[0];
  const float* W = (const float*)d_in[1];
  float* partial = (float*)d_ws;  // 512 * 600 * 4 = 1.2 MB
  float* out = (float*)d_out;
  hipLaunchKernelGGL(socpool_proj, dim3(B_ * BPB), dim3(256), 0, stream,
                     x, W, partial);
  hipLaunchKernelGGL(socpool_eig, dim3(B_), dim3(64), 0, stream,
                     partial, out);
}

// Round 3
// 742.623 us; speedup vs baseline: 1.4971x; 1.4971x over previous
//
#include <hip/hip_runtime.h>
#include <math.h>

// SOCPooling on MI355X (gfx950):
//   x [128,1024,768] f32, W [24,768] f32 -> out [128,300] f32
//
// ROUND 3: streaming-sequential projection.
//   Evidence: R0 (128B/row/visit strided) = 1.13 TB/s effective; R2 (384B
//   bursts) raised HBM counter 574->855 GB/s => burst length is THE lever.
//   Any thread-owns-row + LDS-column-chunk design caps bursts at
//   LDS_tile/256rows ~ 128-512B. So: read x fully sequentially (each wave
//   streams its 64-row slab, 1024B/instr = the 6.3TB/s float4-copy pattern)
//   into REGISTERS, lanes own d-windows (12 floats/row/lane).
//   Cross-lane dot reduction on the VALU pipe: 4x DPP row_ror adds +
//   2x shfl_xor (no LDS pressure). W in LDS (73KB), read as full-wave
//   contiguous ds_read_b128 (conflict-free), amortized over 4 rows/read.
//   S = P^T P accumulated IN REGISTERS: lane owns 9 of 576 (k,l) pairs
//   (e = lane + 64i, k=e/24, l=e%24 -- same mapping eig uses), p[t][k]
//   broadcast via bpermute. NO P buffer, NO in-loop barriers at all.
//   Pipes: HBM 64us || VALU ~63us || LDS ~45us, 2 blocks/CU.
// k2: cov finalize + one-sided Jacobi eigh (UNCHANGED from the verified
//   876us baseline).

#define B_      128
#define T_      1024
#define D_      768
#define K_      24
#define BPB     4        // proj blocks per batch (eig combine factor)
#define NACC    600      // 576 S entries + 24 sums
#define NPAIR   300
#define SWEEPS  8
#define PSTRIDE 28

// rotate-within-16 + add (VALU pipe, no LDS). ctrl: row_ror:N = 0x120|N
template <int CTRL>
__device__ __forceinline__ float dpp_add(float v) {
  int r = __builtin_amdgcn_update_dpp(0, __float_as_int(v), CTRL, 0xF, 0xF,
                                      false);
  return v + __int_as_float(r);
}

// full 64-lane allreduce sum: 4 DPP steps (VALU) + 2 shfl_xor (LDS pipe)
__device__ __forceinline__ float allreduce64(float v) {
  v = dpp_add<0x121>(v);   // ror 1
  v = dpp_add<0x122>(v);   // ror 2
  v = dpp_add<0x124>(v);   // ror 4
  v = dpp_add<0x128>(v);   // ror 8  -> every lane has its 16-group sum
  v += __shfl_xor(v, 16);
  v += __shfl_xor(v, 32);
  return v;
}

__global__ __launch_bounds__(256, 2) void socpool_proj(
    const float* __restrict__ x, const float* __restrict__ W,
    float* __restrict__ partial) {
  __shared__ __align__(16) float WL[K_ * D_];   // 73728 B
  __shared__ float Sbuf[NACC];                  // 2400 B
  const int tid = threadIdx.x;
  const int wv  = tid >> 6;    // wave 0..3
  const int l   = tid & 63;    // lane

  // ---- stage W to LDS (coalesced), zero Sbuf ----
  {
    const float4* Wg4 = (const float4*)W;
    float4* WL4w = (float4*)WL;
#pragma unroll
    for (int i = 0; i < (K_ * D_ / 4) / 256; ++i)   // 18 iters
      WL4w[i * 256 + tid] = Wg4[i * 256 + tid];
  }
  for (int e = tid; e < NACC; e += 256) Sbuf[e] = 0.f;

  // per-lane S-pair indices: e = l + 64*i -> (k,l) of the 24x24 S matrix
  int ki[9], li[9];
#pragma unroll
  for (int i = 0; i < 9; ++i) {
    const int e = l + (i << 6);
    ki[i] = e / K_;
    li[i] = e - ki[i] * K_;
  }

  float Sacc[9];
#pragma unroll
  for (int i = 0; i < 9; ++i) Sacc[i] = 0.f;
  float smacc = 0.f;   // lane<24: column sum partial for k=l

  // wave's 64-row slab; groups of 4 rows; lane l owns floats
  // [s*256 + l*4, +4) of each row (s=0..2) -> fully sequential global reads.
  const int rowbase = blockIdx.x * 256 + wv * 64;
  const float4* x4 = (const float4*)x;
  const float4* WL4 = (const float4*)WL;

  float4 xa[4][3], xb[4][3];

  auto loadg = [&](float4(&buf)[4][3], int g) {
    const size_t base = (size_t)(rowbase + g * 4) * (D_ / 4) + l;
#pragma unroll
    for (int r = 0; r < 4; ++r)
#pragma unroll
      for (int s = 0; s < 3; ++s)
        buf[r][s] = x4[base + r * (D_ / 4) + s * 64];
  };

  auto computeg = [&](const float4(&buf)[4][3]) {
    float pk[4] = {0.f, 0.f, 0.f, 0.f};   // lane k<24 keeps p[row_r][k=l]
#pragma unroll 4
    for (int k = 0; k < K_; ++k) {
      const float4* wp = WL4 + k * (D_ / 4) + l;
      const float4 w0 = wp[0];
      const float4 w1 = wp[64];
      const float4 w2 = wp[128];
#pragma unroll
      for (int r = 0; r < 4; ++r) {
        float a;
        a = buf[r][0].x * w0.x;
        a = fmaf(buf[r][0].y, w0.y, a);
        a = fmaf(buf[r][0].z, w0.z, a);
        a = fmaf(buf[r][0].w, w0.w, a);
        a = fmaf(buf[r][1].x, w1.x, a);
        a = fmaf(buf[r][1].y, w1.y, a);
        a = fmaf(buf[r][1].z, w1.z, a);
        a = fmaf(buf[r][1].w, w1.w, a);
        a = fmaf(buf[r][2].x, w2.x, a);
        a = fmaf(buf[r][2].y, w2.y, a);
        a = fmaf(buf[r][2].z, w2.z, a);
        a = fmaf(buf[r][2].w, w2.w, a);
        a = allreduce64(a);               // full dot p[row_r][k], all lanes
        pk[r] = (l == k) ? a : pk[r];
      }
    }
    // S += p p^T over the 4 rows; p[k] lives in lane k -> bpermute broadcast
#pragma unroll
    for (int r = 0; r < 4; ++r) {
      const float pv = pk[r];
#pragma unroll
      for (int i = 0; i < 9; ++i) {
        const float va = __shfl(pv, ki[i]);
        const float vb = __shfl(pv, li[i]);
        Sacc[i] = fmaf(va, vb, Sacc[i]);
      }
      if (l < K_) smacc += pv;
    }
  };

  __syncthreads();   // W staged, Sbuf zeroed

  // even/odd software pipeline: prefetch next group's 12 loads while
  // computing current (compiler waitcnt tracks xa/xb independently)
  loadg(xa, 0);
  for (int g = 0; g < 16; g += 2) {
    loadg(xb, g + 1);
    computeg(xa);
    if (g + 2 < 16) loadg(xa, g + 2);
    computeg(xb);
  }

  // ---- combine 4 waves' S partials via LDS atomics on the symbol ----
#pragma unroll
  for (int i = 0; i < 9; ++i) atomicAdd(&Sbuf[l + (i << 6)], Sacc[i]);
  if (l < K_) atomicAdd(&Sbuf[576 + l], smacc);
  __syncthreads();
  float* outp = partial + (size_t)blockIdx.x * NACC;
  for (int e = tid; e < NACC; e += 256) outp[e] = Sbuf[e];
}

__global__ __launch_bounds__(64, 1) void socpool_eig(
    const float* __restrict__ partial, float* __restrict__ out) {
  __shared__ float Amat[K_ * 25];
  __shared__ float Qs[K_ * 25];
  __shared__ float lv[K_];
  __shared__ float raw[NACC];
  __shared__ float Xc[K_ * PSTRIDE];  // column-exchange buffer
  const int tid = threadIdx.x;  // 64 threads = 1 wave
  const int b = blockIdx.x;

  // combine the 4 per-block partials
#pragma unroll
  for (int i = 0; i < 10; ++i) {
    int e = tid + (i << 6);
    if (e < NACC) {
      float v = 0.f;
#pragma unroll
      for (int jj = 0; jj < BPB; ++jj)
        v += partial[(size_t)(b * BPB + jj) * NACC + e];
      raw[e] = v;
    }
  }
  __syncthreads();

  const float inv_n   = 1.f / 1024.f;
  const float inv_nm1 = 1.f / (1023.f + 1e-6f);
  float cv[9];
#pragma unroll
  for (int i = 0; i < 9; ++i) {
    int e = tid + (i << 6);            // < 576 always
    int k = e / K_, l = e % K_;
    cv[i] = (raw[e] - raw[576 + k] * raw[576 + l] * inv_n) * inv_nm1;
    Amat[k * 25 + l] = cv[i];
  }
  __syncthreads();
  float tr = 0.f;
#pragma unroll
  for (int k = 0; k < K_; ++k) tr += Amat[k * 25 + k];
  float sym[9];
#pragma unroll
  for (int i = 0; i < 9; ++i) {
    int e = tid + (i << 6);
    int k = e / K_, l = e % K_;
    sym[i] = cv[i] + Amat[l * 25 + k];
  }
  __syncthreads();
  const float sc = 0.5f / (tr + 1e-6f);
#pragma unroll
  for (int i = 0; i < 9; ++i) {
    int e = tid + (i << 6);
    int k = e / K_, l = e % K_;
    Amat[k * 25 + l] = sym[i] * sc + ((k == l) ? 1e-4f : 0.f);
  }
  __syncthreads();

  // ---- one-sided Jacobi: lane j holds column j as float4 Gv[6] ----
  const int j = tid;
  float4 Gv[6];
#pragma unroll
  for (int q = 0; q < 6; ++q) {
    // A symmetric: column j == row j (row read; init-only, alignment moot)
    Gv[q].x = (j < K_) ? Amat[j * 25 + 4*q + 0] : 0.f;
    Gv[q].y = (j < K_) ? Amat[j * 25 + 4*q + 1] : 0.f;
    Gv[q].z = (j < K_) ? Amat[j * 25 + 4*q + 2] : 0.f;
    Gv[q].w = (j < K_) ? Amat[j * 25 + 4*q + 3] : 0.f;
  }

  for (int sweep = 0; sweep < SWEEPS; ++sweep) {
    for (int rr = 0; rr < 23; ++rr) {
      // circle-method round-robin: fixed player 23; inv(2) mod 23 = 12
      int partner;
      if (j == 23) {
        partner = (12 * rr) % 23;
      } else if (j < 23) {
        partner = rr - j;
        if (partner < 0) partner += 23;
        if (partner == j) partner = 23;
      } else {
        partner = j;  // idle lanes: identity rotation below
      }
      // exchange via LDS: 6 b128 writes + 6 b128 reads (stride 28 -> no
      // bank conflicts), instead of 25 latency-serialized ds_bpermute
      if (j < K_) {
#pragma unroll
        for (int q = 0; q < 6; ++q)
          *(float4*)(&Xc[j * PSTRIDE + (q << 2)]) = Gv[q];
      }
      __syncthreads();
      const int pcol = (partner < K_) ? partner : 0;
      float4 O[6];
#pragma unroll
      for (int q = 0; q < 6; ++q)
        O[q] = *(const float4*)(&Xc[pcol * PSTRIDE + (q << 2)]);
      // three dots, 12 independent FMA chains
      float a0=0.f,a1=0.f,a2=0.f,a3=0.f;   // nn  = G.G
      float b0=0.f,b1=0.f,b2=0.f,b3=0.f;   // nno = O.O
      float c0=0.f,c1=0.f,c2=0.f,c3=0.f;   // gpq = G.O
#pragma unroll
      for (int q = 0; q < 6; ++q) {
        a0 = fmaf(Gv[q].x, Gv[q].x, a0); a1 = fmaf(Gv[q].y, Gv[q].y, a1);
        a2 = fmaf(Gv[q].z, Gv[q].z, a2); a3 = fmaf(Gv[q].w, Gv[q].w, a3);
        b0 = fmaf(O[q].x, O[q].x, b0);   b1 = fmaf(O[q].y, O[q].y, b1);
        b2 = fmaf(O[q].z, O[q].z, b2);   b3 = fmaf(O[q].w, O[q].w, b3);
        c0 = fmaf(Gv[q].x, O[q].x, c0);  c1 = fmaf(Gv[q].y, O[q].y, c1);
        c2 = fmaf(Gv[q].z, O[q].z, c2);  c3 = fmaf(Gv[q].w, O[q].w, c3);
      }
      float nn  = (a0 + a1) + (a2 + a3);
      float nno = (b0 + b1) + (b2 + b3);
      float gpq = (c0 + c1) + (c2 + c3);
      const bool low = (j < partner);
      float app = low ? nn : nno;
      float aqq = low ? nno : nn;
      float cc = 1.f, ss = 0.f;
      if (j != partner && fabsf(gpq) > 1e-30f) {
        float tau = (aqq - app) / (2.f * gpq);
        float t = 1.f / (fabsf(tau) + sqrtf(1.f + tau * tau));
        if (tau < 0.f) t = -t;
        cc = 1.f / sqrtf(1.f + t * t);
        ss = t * cc;
      }
      float sg = low ? -ss : ss;  // p' = c p - s q ; q' = s p + c q
#pragma unroll
      for (int q = 0; q < 6; ++q) {
        Gv[q].x = fmaf(sg, O[q].x, cc * Gv[q].x);
        Gv[q].y = fmaf(sg, O[q].y, cc * Gv[q].y);
        Gv[q].z = fmaf(sg, O[q].z, cc * Gv[q].z);
        Gv[q].w = fmaf(sg, O[q].w, cc * Gv[q].w);
      }
      __syncthreads();  // Xc reuse next round
    }
  }

  // eigenvalues = column norms (A SPD), eigenvectors = normalized columns
  if (j < K_) {
    float n0=0.f,n1=0.f,n2=0.f,n3=0.f;
#pragma unroll
    for (int q = 0; q < 6; ++q) {
      n0 = fmaf(Gv[q].x, Gv[q].x, n0); n1 = fmaf(Gv[q].y, Gv[q].y, n1);
      n2 = fmaf(Gv[q].z, Gv[q].z, n2); n3 = fmaf(Gv[q].w, Gv[q].w, n3);
    }
    float lam = sqrtf((n0 + n1) + (n2 + n3));
    lv[j] = logf(fmaxf(lam, 1e-6f));
    float inv = 1.f / fmaxf(lam, 1e-20f);
#pragma unroll
    for (int q = 0; q < 6; ++q) {
      Qs[(4*q + 0) * 25 + j] = Gv[q].x * inv;
      Qs[(4*q + 1) * 25 + j] = Gv[q].y * inv;
      Qs[(4*q + 2) * 25 + j] = Gv[q].z * inv;
      Qs[(4*q + 3) * 25 + j] = Gv[q].w * inv;
    }
  }
  __syncthreads();

  // log_cov = Q diag(lv) Q^T, upper triangle row-major (matches triu_indices)
  for (int e = tid; e < NPAIR; e += 64) {
    int i = 0, base = 0;
    while (i < K_ - 1 && base + (K_ - i) <= e) { base += K_ - i; ++i; }
    int jj = i + (e - base);
    float sum = 0.f;
#pragma unroll
    for (int k = 0; k < K_; ++k)
      sum = fmaf(Qs[i * 25 + k] * lv[k], Qs[jj * 25 + k], sum);
    out[(size_t)b * NPAIR + e] = sum;
  }
}

extern "C" void kernel_launch(void* const* d_in, const int* in_sizes, int n_in,
                              void* d_out, int out_size, void* d_ws, size_t ws_size,
                              hipStream_t stream) {
  const float* x = (const float*)d_in[0];
  const float* W = (const float*)d_in[1];
  float* partial = (float*)d_ws;  // 512 * 600 * 4 = 1.2 MB
  float* out = (float*)d_out;
  hipLaunchKernelGGL(socpool_proj, dim3(512), dim3(256), 0, stream,
                     x, W, partial);
  hipLaunchKernelGGL(socpool_eig, dim3(B_), dim3(64), 0, stream,
                     partial, out);
}